// Round 1
// baseline (294.516 us; speedup 1.0000x reference)
//
#include <hip/hip_runtime.h>

// CRF log-partition forward on MI355X.
// B=64 blocks (one per sequence), 512 threads: quad of 4 lanes per tag j,
// lane k owns rows i in [32k, 32k+32) of E_ij = exp2(T_ij * log2e).
// Linear-domain recurrence with scalar exponent o:
//   S = sum_i p_i ; dot_j = sum_i p_i E_ij ; p'_j = exp2(e_tj*log2e)*dot_j/S ;
//   o += log2(S)
// which is exactly alpha2_j = o + log2(p_j) in base-2 log domain.

#define LOG2E 1.4426950408889634f
#define LN2   0.6931471805599453f

__global__ __launch_bounds__(512) void crf_forward(
    const float* __restrict__ emissions,   // [B, L, 1, N] -> [64, 512, 128]
    const float* __restrict__ transitions, // [1, N, N]
    const float* __restrict__ start_t,     // [1, N]
    const float* __restrict__ end_t,       // [1, N]
    const int*   __restrict__ lengths,     // [B]
    float* __restrict__ out)               // [B, 1]
{
    constexpr int N = 128;
    constexpr int L = 512;
    const int b   = blockIdx.x;
    const int tid = threadIdx.x;
    const int j   = tid >> 2;      // output tag 0..127
    const int k   = tid & 3;       // quad slot: i-range [32k, 32k+32)

    __shared__ alignas(16) float pbuf[2][N];
    __shared__ float wsum[8];

    // ---- precompute E chunk in registers: E[ii] = exp2(T[(32k+ii)][j] * log2e)
    float E[32];
    #pragma unroll
    for (int ii = 0; ii < 32; ++ii) {
        float tv = transitions[(k * 32 + ii) * N + j];
        E[ii] = __builtin_amdgcn_exp2f(tv * LOG2E);
    }

    const int len = lengths[b];
    const float* eb = emissions + (size_t)b * L * N;

    // ---- init: p_j = exp2((start_j + e0_j) * log2e), o = 0
    float a0 = (start_t[j] + eb[j]) * LOG2E;
    float p  = __builtin_amdgcn_exp2f(a0);
    float o  = 0.0f;
    if (k == 0) pbuf[0][j] = p;
    __syncthreads();

    // software prefetch of next emission value
    float e_next = eb[(len > 1 ? 1 : 0) * N + j];

    int cur = 0;
    for (int t = 1; t < len; ++t) {
        float e_cur = e_next;
        int tn = (t + 1 < len) ? (t + 1) : (len - 1);
        e_next = eb[tn * N + j];

        // read p chunk [32k, 32k+32) as 8x float4 (broadcast across 16 lanes each)
        const float4* pv = reinterpret_cast<const float4*>(&pbuf[cur][k * 32]);
        float dot = 0.0f, S = 0.0f;
        #pragma unroll
        for (int w = 0; w < 8; ++w) {
            float4 v = pv[w];
            dot = fmaf(E[w * 4 + 0], v.x, dot); S += v.x;
            dot = fmaf(E[w * 4 + 1], v.y, dot); S += v.y;
            dot = fmaf(E[w * 4 + 2], v.z, dot); S += v.z;
            dot = fmaf(E[w * 4 + 3], v.w, dot); S += v.w;
        }
        // combine the 4 quad partials (lanes 4j..4j+3); bitwise-identical S on all lanes
        dot += __shfl_xor(dot, 1); S += __shfl_xor(S, 1);
        dot += __shfl_xor(dot, 2); S += __shfl_xor(S, 2);

        float rS   = __builtin_amdgcn_rcpf(S);
        float expE = __builtin_amdgcn_exp2f(e_cur * LOG2E);
        p = expE * dot * rS;
        o += __builtin_amdgcn_logf(S);   // log2(S), uniform across the block

        cur ^= 1;
        if (k == 0) pbuf[cur][j] = p;
        __syncthreads();
    }

    // ---- finalize: out[b] = ln2 * (o + log2(sum_j p_j * exp2(end_j*log2e)))
    float vend = p * __builtin_amdgcn_exp2f(end_t[j] * LOG2E);
    float v = vend * 0.25f;   // each j replicated 4x across its quad
    #pragma unroll
    for (int m = 1; m < 64; m <<= 1) v += __shfl_xor(v, m);
    const int wave = tid >> 6;
    const int lane = tid & 63;
    if (lane == 0) wsum[wave] = v;
    __syncthreads();
    if (tid == 0) {
        float tot = 0.0f;
        #pragma unroll
        for (int w = 0; w < 8; ++w) tot += wsum[w];
        out[b] = LN2 * (o + __builtin_amdgcn_logf(tot));
    }
}

extern "C" void kernel_launch(void* const* d_in, const int* in_sizes, int n_in,
                              void* d_out, int out_size, void* d_ws, size_t ws_size,
                              hipStream_t stream) {
    const float* emissions   = (const float*)d_in[0];
    const float* transitions = (const float*)d_in[1];
    const float* start_t     = (const float*)d_in[2];
    const float* end_t       = (const float*)d_in[3];
    const int*   lengths     = (const int*)d_in[4];
    float* out = (float*)d_out;

    crf_forward<<<dim3(64), dim3(512), 0, stream>>>(
        emissions, transitions, start_t, end_t, lengths, out);
}

// Round 2
// 288.836 us; speedup vs baseline: 1.0197x; 1.0197x over previous
//
#include <hip/hip_runtime.h>

// CRF log-partition forward, MI355X. 64 blocks (1 per sequence) x 128 threads
// (2 waves). Lane owns a 32i x 4j tile of E = exp(T): k = tid&3 -> i in
// [32k,32k+32), g = tid>>2 -> j in [4g,4g+4). After a DPP quad butterfly the
// lane keeps dot for j == tid (4g+k == tid), so emissions/p-writes are
// contiguous in tid.
//
// Linear-domain recurrence with exact power-of-2 renormalization:
//   q'_j = exp2(e_j*log2e) * (sum_i q_i E_ij) * 2^(-eS),  eS = exponent(q_0)
//   o    += eS   (integer, exact)
// alpha_j = ln2 * (o + log2 q_j). Final: ln2*(o + log2 sum_j q_j*exp(end_j)).

#define LOG2E 1.4426950408889634f
#define LN2   0.6931471805599453f

template <int CTRL>
__device__ __forceinline__ float dpp_f(float x) {
    return __int_as_float(
        __builtin_amdgcn_mov_dpp(__float_as_int(x), CTRL, 0xF, 0xF, false));
}
// quad_perm codes: xor1 = [1,0,3,2] = 0xB1, xor2 = [2,3,0,1] = 0x4E,
// broadcast lane0 of quad = [0,0,0,0] = 0x00

__global__ __launch_bounds__(128, 1) void crf_forward(
    const float* __restrict__ emissions,   // [64, 512, 128]
    const float* __restrict__ transitions, // [128, 128]
    const float* __restrict__ start_t,     // [128]
    const float* __restrict__ end_t,       // [128]
    const int*   __restrict__ lengths,     // [64]
    float* __restrict__ out)               // [64]
{
    constexpr int N = 128;
    constexpr int L = 512;
    constexpr int PW = 36;   // padded words per 32-float chunk (16B aligned, disjoint banks)
    const int b   = blockIdx.x;
    const int tid = threadIdx.x;
    const int g   = tid >> 2;   // j-quad: j in [4g, 4g+4)
    const int k   = tid & 3;    // i-chunk: i in [32k, 32k+32)

    // p_i lives at word (i>>5)*PW + (i&31); chunk k base = k*PW words (144 B, 16B aligned)
    __shared__ alignas(16) float pbuf[2][4 * PW];
    __shared__ float wsum[2];

    // ---- one-time: E tile in registers. E[ii*4+jj] = exp2(T[32k+ii][4g+jj]*log2e)
    float E[128];
    {
        const float* tb = transitions + (size_t)(32 * k) * N + 4 * g;
        #pragma unroll
        for (int ii = 0; ii < 32; ++ii) {
            float4 tv = *reinterpret_cast<const float4*>(tb + (size_t)ii * N);
            E[ii * 4 + 0] = __builtin_amdgcn_exp2f(tv.x * LOG2E);
            E[ii * 4 + 1] = __builtin_amdgcn_exp2f(tv.y * LOG2E);
            E[ii * 4 + 2] = __builtin_amdgcn_exp2f(tv.z * LOG2E);
            E[ii * 4 + 3] = __builtin_amdgcn_exp2f(tv.w * LOG2E);
        }
    }

    const int len = lengths[b];
    const float* eb = emissions + (size_t)b * L * N;

    // ---- init: q_j = exp2((start_j + e0_j)*log2e), j = tid
    float p = __builtin_amdgcn_exp2f((start_t[tid] + eb[tid]) * LOG2E);
    int o = 0;
    pbuf[0][(tid >> 5) * PW + (tid & 31)] = p;
    __syncthreads();

    float e_cur = eb[(len > 1 ? 1 : 0) * N + tid];   // emission for t=1

    int cur = 0;
    for (int t = 1; t < len; ++t) {
        // prefetch next emission (clamped)
        int tn = (t + 1 < len) ? (t + 1) : (len - 1);
        float e_next = eb[(size_t)tn * N + tid];

        // read my 32-float chunk as 8x float4 (16 lanes broadcast per address)
        const float4* pv =
            reinterpret_cast<const float4*>(&pbuf[cur][k * PW]);
        float4 v[8];
        #pragma unroll
        for (int w = 0; w < 8; ++w) v[w] = pv[w];

        // block-uniform normalizer from previous q_0 (chunk k=0, word 0):
        // exact power-of-2 -> no transcendental, off the critical tail
        float s0 = dpp_f<0x00>(v[0].x);           // quad-broadcast of k==0 lane
        int eS = (int)((__float_as_uint(s0) >> 23) & 0xFFu) - 127;
        o += eS;
        float scale = __uint_as_float((unsigned)(127 - eS) << 23);

        float expE = __builtin_amdgcn_exp2f(e_cur * LOG2E);

        // 4 dot products over the 32i x 4j tile
        float d0 = 0.f, d1 = 0.f, d2 = 0.f, d3 = 0.f;
        #pragma unroll
        for (int w = 0; w < 8; ++w) {
            #pragma unroll
            for (int e = 0; e < 4; ++e) {
                float pe = (&v[w].x)[e];
                const int base = (w * 4 + e) * 4;
                d0 = fmaf(pe, E[base + 0], d0);
                d1 = fmaf(pe, E[base + 1], d1);
                d2 = fmaf(pe, E[base + 2], d2);
                d3 = fmaf(pe, E[base + 3], d3);
            }
        }

        // quad butterfly: all 4 lanes get full sums, then keep d[k] (j == tid)
        d0 += dpp_f<0xB1>(d0); d1 += dpp_f<0xB1>(d1);
        d2 += dpp_f<0xB1>(d2); d3 += dpp_f<0xB1>(d3);
        d0 += dpp_f<0x4E>(d0); d1 += dpp_f<0x4E>(d1);
        d2 += dpp_f<0x4E>(d2); d3 += dpp_f<0x4E>(d3);
        float dlo = (k & 1) ? d1 : d0;
        float dhi = (k & 1) ? d3 : d2;
        float dm  = (k & 2) ? dhi : dlo;

        p = expE * dm * scale;
        pbuf[cur ^ 1][(tid >> 5) * PW + (tid & 31)] = p;
        e_cur = e_next;
        cur ^= 1;
        __syncthreads();
    }

    // ---- finalize: out[b] = ln2 * (o + log2(sum_j q_j * exp2(end_j*log2e)))
    float vend = p * __builtin_amdgcn_exp2f(end_t[tid] * LOG2E);
    #pragma unroll
    for (int m = 1; m < 64; m <<= 1) vend += __shfl_xor(vend, m);
    if ((tid & 63) == 0) wsum[tid >> 6] = vend;
    __syncthreads();
    if (tid == 0)
        out[b] = LN2 * ((float)o + __builtin_amdgcn_logf(wsum[0] + wsum[1]));
}

extern "C" void kernel_launch(void* const* d_in, const int* in_sizes, int n_in,
                              void* d_out, int out_size, void* d_ws, size_t ws_size,
                              hipStream_t stream) {
    const float* emissions   = (const float*)d_in[0];
    const float* transitions = (const float*)d_in[1];
    const float* start_t     = (const float*)d_in[2];
    const float* end_t       = (const float*)d_in[3];
    const int*   lengths     = (const int*)d_in[4];
    float* out = (float*)d_out;

    crf_forward<<<dim3(64), dim3(128), 0, stream>>>(
        emissions, transitions, start_t, end_t, lengths, out);
}

// Round 3
// 253.788 us; speedup vs baseline: 1.1605x; 1.1381x over previous
//
#include <hip/hip_runtime.h>

// CRF log-partition forward, MI355X. 64 blocks (1 per sequence) x 256 threads
// (4 waves, 1/SIMD). Lane tile: k = tid&7 -> i-chunk [16k,16k+16),
// g = tid>>3 -> j in [4g,4g+4). 64 FMA/lane/step (128 issue-cyc per SIMD),
// 16 KB/step LDS return, one barrier per step.
// Combine over the 8 k-lanes: DPP quad xor1/xor2 + ds_swizzle xor4; lanes
// k<4 each write one output tag j = 4g+k (32 consecutive tags per wave ->
// conflict-free b32 stores).
//
// Linear-domain recurrence with exact power-of-2 renormalization:
//   q'_j = exp2(e_j*log2e) * (sum_i q_i E_ij) * 2^(-eS),  eS = exponent(q_0)
//   o    += eS   (integer, exact)
// alpha_j = ln2 * (o + log2 q_j). Final: ln2*(o + log2 sum_j q_j*exp(end_j)).

#define LOG2E 1.4426950408889634f
#define LN2   0.6931471805599453f

template <int CTRL>
__device__ __forceinline__ float dpp_f(float x) {
    return __int_as_float(
        __builtin_amdgcn_mov_dpp(__float_as_int(x), CTRL, 0xF, 0xF, false));
}
// quad_perm codes: xor1 = 0xB1, xor2 = 0x4E
__device__ __forceinline__ float swz_xor4(float x) {
    // BitMode: offset = (xor<<10)|(or<<5)|and ; xor=4, and=0x1F
    return __int_as_float(
        __builtin_amdgcn_ds_swizzle(__float_as_int(x), (4 << 10) | 0x1F));
}

__global__ __launch_bounds__(256, 1) void crf_forward(
    const float* __restrict__ emissions,   // [64, 512, 128]
    const float* __restrict__ transitions, // [128, 128]
    const float* __restrict__ start_t,     // [128]
    const float* __restrict__ end_t,       // [128]
    const int*   __restrict__ lengths,     // [64]
    float* __restrict__ out)               // [64]
{
    constexpr int N = 128;
    constexpr int L = 512;
    constexpr int PW = 20;   // 16 floats + 4 pad per chunk (80 B, 16B-aligned)
    const int b   = blockIdx.x;
    const int tid = threadIdx.x;
    const int g   = tid >> 3;            // j-group: j in [4g, 4g+4)
    const int k   = tid & 7;             // i-chunk: i in [16k, 16k+16)
    const int jw  = 4 * g + (k & 3);     // this lane's output tag (writer iff k<4)

    __shared__ alignas(16) float pbuf[2][8 * PW];
    __shared__ float wsum[2];

    // ---- one-time: E tile in registers. E[ii*4+jj] = exp2(T[16k+ii][4g+jj]*log2e)
    float E[64];
    {
        const float* tb = transitions + (size_t)(16 * k) * N + 4 * g;
        #pragma unroll
        for (int ii = 0; ii < 16; ++ii) {
            float4 tv = *reinterpret_cast<const float4*>(tb + (size_t)ii * N);
            E[ii * 4 + 0] = __builtin_amdgcn_exp2f(tv.x * LOG2E);
            E[ii * 4 + 1] = __builtin_amdgcn_exp2f(tv.y * LOG2E);
            E[ii * 4 + 2] = __builtin_amdgcn_exp2f(tv.z * LOG2E);
            E[ii * 4 + 3] = __builtin_amdgcn_exp2f(tv.w * LOG2E);
        }
    }

    const int len = lengths[b];
    const float* eb = emissions + (size_t)b * L * N;

    // ---- init: q_j = exp2((start_j + e0_j)*log2e)
    if (tid < N) {
        float q = __builtin_amdgcn_exp2f((start_t[tid] + eb[tid]) * LOG2E);
        pbuf[0][(tid >> 4) * PW + (tid & 15)] = q;
    }
    int o = 0;
    __syncthreads();

    float e_cur = eb[(size_t)(len > 1 ? 1 : 0) * N + jw];   // emission for t=1

    int cur = 0;
    for (int t = 1; t < len; ++t) {
        // prefetch next emission (clamped)
        int tn = (t + 1 < len) ? (t + 1) : (len - 1);
        float e_next = eb[(size_t)tn * N + jw];

        // normalizer source + my 16-float chunk (4x b128, disjoint banks via pad)
        float p0 = pbuf[cur][0];
        const float4* pv = reinterpret_cast<const float4*>(&pbuf[cur][k * PW]);
        float4 v[4];
        #pragma unroll
        for (int w = 0; w < 4; ++w) v[w] = pv[w];

        float expE = __builtin_amdgcn_exp2f(e_cur * LOG2E);
        int eS = (int)((__float_as_uint(p0) >> 23) & 0xFFu) - 127;
        o += eS;
        float scale = __uint_as_float((unsigned)(127 - eS) << 23);

        // 4 dot products over the 16i x 4j tile
        float d0 = 0.f, d1 = 0.f, d2 = 0.f, d3 = 0.f;
        #pragma unroll
        for (int w = 0; w < 4; ++w) {
            #pragma unroll
            for (int e = 0; e < 4; ++e) {
                float pe = (&v[w].x)[e];
                const int base = (w * 4 + e) * 4;
                d0 = fmaf(pe, E[base + 0], d0);
                d1 = fmaf(pe, E[base + 1], d1);
                d2 = fmaf(pe, E[base + 2], d2);
                d3 = fmaf(pe, E[base + 3], d3);
            }
        }

        // combine the 8 k-partials: xor1 (DPP), xor2 (DPP), xor4 (swizzle)
        d0 += dpp_f<0xB1>(d0); d1 += dpp_f<0xB1>(d1);
        d2 += dpp_f<0xB1>(d2); d3 += dpp_f<0xB1>(d3);
        d0 += dpp_f<0x4E>(d0); d1 += dpp_f<0x4E>(d1);
        d2 += dpp_f<0x4E>(d2); d3 += dpp_f<0x4E>(d3);
        d0 += swz_xor4(d0); d1 += swz_xor4(d1);
        d2 += swz_xor4(d2); d3 += swz_xor4(d3);

        // lane k<4 owns tag j = 4g+k
        float dlo = (k & 1) ? d1 : d0;
        float dhi = (k & 1) ? d3 : d2;
        float dm  = (k & 2) ? dhi : dlo;

        float pn = expE * dm * scale;
        cur ^= 1;
        if (k < 4) pbuf[cur][(jw >> 4) * PW + (jw & 15)] = pn;
        e_cur = e_next;
        __syncthreads();
    }

    // ---- finalize: out[b] = ln2 * (o + log2(sum_j q_j * exp2(end_j*log2e)))
    if (tid < N) {
        float q = pbuf[cur][(tid >> 4) * PW + (tid & 15)];
        float vend = q * __builtin_amdgcn_exp2f(end_t[tid] * LOG2E);
        #pragma unroll
        for (int m = 1; m < 64; m <<= 1) vend += __shfl_xor(vend, m);
        if ((tid & 63) == 0) wsum[tid >> 6] = vend;
    }
    __syncthreads();
    if (tid == 0)
        out[b] = LN2 * ((float)o + __builtin_amdgcn_logf(wsum[0] + wsum[1]));
}

extern "C" void kernel_launch(void* const* d_in, const int* in_sizes, int n_in,
                              void* d_out, int out_size, void* d_ws, size_t ws_size,
                              hipStream_t stream) {
    const float* emissions   = (const float*)d_in[0];
    const float* transitions = (const float*)d_in[1];
    const float* start_t     = (const float*)d_in[2];
    const float* end_t       = (const float*)d_in[3];
    const int*   lengths     = (const int*)d_in[4];
    float* out = (float*)d_out;

    crf_forward<<<dim3(64), dim3(256), 0, stream>>>(
        emissions, transitions, start_t, end_t, lengths, out);
}

// Round 4
// 217.798 us; speedup vs baseline: 1.3522x; 1.1652x over previous
//
#include <hip/hip_runtime.h>

// CRF log-partition forward, MI355X. 64 blocks (1 per sequence) x 256 threads
// (4 waves, 1/SIMD). Lane tile: k = tid&7 -> i-chunk [16k,16k+16),
// g = tid>>3 -> j in [4g,4g+4). Dot products kept as two float2 accumulators
// (v_pk_fma_f32). Combine: DPP quad butterfly (xor1,xor2), THEN select the
// lane's target column (lanes k and k^4 share column k&3), then a single
// ds_swizzle xor4 + add. Writers k<4 store tag j = 4g+k.
//
// Linear-domain recurrence with exact power-of-2 renormalization:
//   q'_j = exp2(e_j*log2e) * (sum_i q_i E_ij) * 2^(-eS),  eS = exponent(q_0)
//   o    += eS   (integer, exact)
// alpha_j = ln2 * (o + log2 q_j). Final: ln2*(o + log2 sum_j q_j*exp(end_j)).

#define LOG2E 1.4426950408889634f
#define LN2   0.6931471805599453f

typedef float f2 __attribute__((ext_vector_type(2)));

template <int CTRL>
__device__ __forceinline__ float dpp_f(float x) {
    return __int_as_float(
        __builtin_amdgcn_mov_dpp(__float_as_int(x), CTRL, 0xF, 0xF, false));
}
template <int CTRL>
__device__ __forceinline__ f2 dpp_f2(f2 x) {
    f2 r;
    r.x = dpp_f<CTRL>(x.x);
    r.y = dpp_f<CTRL>(x.y);
    return r;
}
// quad_perm codes: xor1 = 0xB1, xor2 = 0x4E
__device__ __forceinline__ float swz_xor4(float x) {
    // BitMode: offset = (xor<<10)|(or<<5)|and ; xor=4, and=0x1F
    return __int_as_float(
        __builtin_amdgcn_ds_swizzle(__float_as_int(x), (4 << 10) | 0x1F));
}

__global__ __launch_bounds__(256, 1) void crf_forward(
    const float* __restrict__ emissions,   // [64, 512, 128]
    const float* __restrict__ transitions, // [128, 128]
    const float* __restrict__ start_t,     // [128]
    const float* __restrict__ end_t,       // [128]
    const int*   __restrict__ lengths,     // [64]
    float* __restrict__ out)               // [64]
{
    constexpr int N = 128;
    constexpr int L = 512;
    constexpr int PW = 20;   // 16 floats + 4 pad per chunk (80 B, 16B-aligned)
    const int b   = blockIdx.x;
    const int tid = threadIdx.x;
    const int g   = tid >> 3;            // j-group: j in [4g, 4g+4)
    const int k   = tid & 7;             // i-chunk: i in [16k, 16k+16)
    const int jw  = 4 * g + (k & 3);     // this lane's output tag (writer iff k<4)

    __shared__ alignas(16) float pbuf[2][8 * PW];
    __shared__ float wsum[2];

    // ---- one-time: E tile in registers as float2 column-pairs.
    // E01[ii] = exp(T[16k+ii][4g + {0,1}]), E23[ii] = exp(T[16k+ii][4g + {2,3}])
    f2 E01[16], E23[16];
    {
        const float* tb = transitions + (size_t)(16 * k) * N + 4 * g;
        #pragma unroll
        for (int ii = 0; ii < 16; ++ii) {
            float4 tv = *reinterpret_cast<const float4*>(tb + (size_t)ii * N);
            E01[ii].x = __builtin_amdgcn_exp2f(tv.x * LOG2E);
            E01[ii].y = __builtin_amdgcn_exp2f(tv.y * LOG2E);
            E23[ii].x = __builtin_amdgcn_exp2f(tv.z * LOG2E);
            E23[ii].y = __builtin_amdgcn_exp2f(tv.w * LOG2E);
        }
    }

    const int len = lengths[b];
    const float* eb = emissions + (size_t)b * L * N;

    // ---- init: q_j = exp2((start_j + e0_j)*log2e)
    if (tid < N) {
        float q = __builtin_amdgcn_exp2f((start_t[tid] + eb[tid]) * LOG2E);
        pbuf[0][(tid >> 4) * PW + (tid & 15)] = q;
    }
    int o = 0;
    __syncthreads();

    float e_cur = eb[(size_t)(len > 1 ? 1 : 0) * N + jw];   // emission for t=1

    int cur = 0;
    for (int t = 1; t < len; ++t) {
        // prefetch next emission (clamped)
        int tn = (t + 1 < len) ? (t + 1) : (len - 1);
        float e_next = eb[(size_t)tn * N + jw];

        // normalizer source + my 16-float chunk (4x b128, disjoint banks via pad)
        float p0 = pbuf[cur][0];
        const float4* pv = reinterpret_cast<const float4*>(&pbuf[cur][k * PW]);
        float4 v[4];
        #pragma unroll
        for (int w = 0; w < 4; ++w) v[w] = pv[w];

        float expE = __builtin_amdgcn_exp2f(e_cur * LOG2E);
        int eS = (int)((__float_as_uint(p0) >> 23) & 0xFFu) - 127;
        o += eS;
        float scale = __uint_as_float((unsigned)(127 - eS) << 23);

        // two packed dot products over the 16i x 4j tile (v_pk_fma_f32)
        f2 d01 = {0.f, 0.f}, d23 = {0.f, 0.f};
        #pragma unroll
        for (int w = 0; w < 4; ++w) {
            #pragma unroll
            for (int e = 0; e < 4; ++e) {
                float pe = (&v[w].x)[e];
                f2 pp = {pe, pe};
                const int ii = w * 4 + e;
                d01 = __builtin_elementwise_fma(pp, E01[ii], d01);
                d23 = __builtin_elementwise_fma(pp, E23[ii], d23);
            }
        }

        // quad butterfly (DPP): after xor1+xor2 every quad lane has full
        // quad-sums of all 4 columns.
        d01 += dpp_f2<0xB1>(d01); d23 += dpp_f2<0xB1>(d23);
        d01 += dpp_f2<0x4E>(d01); d23 += dpp_f2<0x4E>(d23);

        // select target column FIRST (lanes k and k^4 pick the same col k&3),
        // then a single xor4 swizzle finishes the 8-way reduction.
        f2    dsel = (k & 2) ? d23 : d01;
        float dm   = (k & 1) ? dsel.y : dsel.x;
        dm += swz_xor4(dm);

        float pn = expE * dm * scale;
        cur ^= 1;
        if (k < 4) pbuf[cur][(jw >> 4) * PW + (jw & 15)] = pn;
        e_cur = e_next;
        __syncthreads();
    }

    // ---- finalize: out[b] = ln2 * (o + log2(sum_j q_j * exp2(end_j*log2e)))
    if (tid < N) {
        float q = pbuf[cur][(tid >> 4) * PW + (tid & 15)];
        float vend = q * __builtin_amdgcn_exp2f(end_t[tid] * LOG2E);
        #pragma unroll
        for (int m = 1; m < 64; m <<= 1) vend += __shfl_xor(vend, m);
        if ((tid & 63) == 0) wsum[tid >> 6] = vend;
    }
    __syncthreads();
    if (tid == 0)
        out[b] = LN2 * ((float)o + __builtin_amdgcn_logf(wsum[0] + wsum[1]));
}

extern "C" void kernel_launch(void* const* d_in, const int* in_sizes, int n_in,
                              void* d_out, int out_size, void* d_ws, size_t ws_size,
                              hipStream_t stream) {
    const float* emissions   = (const float*)d_in[0];
    const float* transitions = (const float*)d_in[1];
    const float* start_t     = (const float*)d_in[2];
    const float* end_t       = (const float*)d_in[3];
    const int*   lengths     = (const int*)d_in[4];
    float* out = (float*)d_out;

    crf_forward<<<dim3(64), dim3(256), 0, stream>>>(
        emissions, transitions, start_t, end_t, lengths, out);
}